// Round 11
// baseline (779.309 us; speedup 1.0000x reference)
//
#include <hip/hip_runtime.h>

// ---------------------------------------------------------------------------
// StructuralCausalModel: 3 layers x 32 vars sequential scan, BATCH=512.
// R11: R9/R10 were CU-VMEM-port bound: each of the 2 co-resident blocks
// streamed the full 288 KB weight set per step (576 KB/CU/step ~ 45 B/cyc
// = 12.8k cyc). Merge them: ONE 1024-thread block per CU (NBLK=256),
// BTILE=2 rows in the M=16 MFMA tile, weights fully N-partitioned across
// 16 waves (pa/W3: 16 tiles -> 1/wave; W1/W2: 8 tiles -> waves 0-7 while
// waves 8-11 run delta-pc). Per-CU stream halves to 288 KB/step with the
// same 16-wave TLP. vals in LDS (2 rows, 32 KB).
// ---------------------------------------------------------------------------

typedef __bf16 bf16x8 __attribute__((ext_vector_type(8)));
typedef float  f32x4  __attribute__((ext_vector_type(4)));

#define N_VARS 32
#define NBLK 256

// ws element offsets (bf16 region starts at byte 4096; adjT f32 at byte 0)
#define ELOFF_PA 0
#define ELOFF_W1 65536
#define ELOFF_W2 1114112
#define ELOFF_W3 1638400
// total bf16 el = 2686976 -> ws bytes = 4096 + 5373952

__device__ __forceinline__ unsigned short f2b(float f) {
    unsigned u = __float_as_uint(f);
    u += 0x7FFFu + ((u >> 16) & 1u);
    return (unsigned short)(u >> 16);
}

// lgkm-only barrier: LDS ordering enforced, global loads stay in flight.
__device__ __forceinline__ void bar_lds() {
    asm volatile("s_waitcnt lgkmcnt(0)\n\ts_barrier" ::: "memory");
}

// erf via Abramowitz-Stegun 7.1.25, 3 terms (|err| <= 2.5e-5)
__device__ __forceinline__ float gelu_e(float x) {
    float z  = x * 0.7071067811865476f;
    float az = fabsf(z);
    float t  = __builtin_amdgcn_rcpf(1.0f + 0.47047f * az);
    float p  = t * (0.3480242f + t * (-0.0958798f + t * 0.7478556f));
    float e  = 1.0f - p * __expf(-z * z);
    float er = (z < 0.0f) ? -e : e;
    return 0.5f * x * (1.0f + er);
}

// ---------------------------------------------------------------------------
// Prep (2569 blocks x 256): [0,520) weight swizzle via LDS tile (coalesced);
// 520 adjacency; [521,2569) noise encoder NE -> d_out (8 rows/block).
// B-frag (16x16x32): lane l, elem j -> k = ks*32+(l>>4)*8+j, n = nt*16+(l&15)
// ---------------------------------------------------------------------------
__global__ void prep_all(const float* __restrict__ paW, const float* __restrict__ mW1,
                         const float* __restrict__ mW2, const float* __restrict__ mW3,
                         const float* __restrict__ edge, unsigned short* __restrict__ wsb,
                         float* __restrict__ adjT,
                         const float* __restrict__ noise, const float* __restrict__ neW,
                         const float* __restrict__ neb, float* __restrict__ outp) {
    __shared__ unsigned short tile[32 * 256];
    const int c = blockIdx.x, tid = threadIdx.x;
    if (c < 520) {
        const float* src; unsigned short* dst; int N, KS, ks;
        if (c < 8)        { src = paW;                     dst = wsb + ELOFF_PA;             N = 256; KS = 8; ks = c; }
        else if (c < 264) { int v = (c - 8) >> 3;   ks = (c - 8) & 7;
                            src = mW1 + v * 32768;         dst = wsb + ELOFF_W1 + v * 32768; N = 128; KS = 8; }
        else if (c < 392) { int v = (c - 264) >> 2; ks = (c - 264) & 3;
                            src = mW2 + v * 16384;         dst = wsb + ELOFF_W2 + v * 16384; N = 128; KS = 4; }
        else              { int v = (c - 392) >> 2; ks = (c - 392) & 3;
                            src = mW3 + v * 32768;         dst = wsb + ELOFF_W3 + v * 32768; N = 256; KS = 4; }
        const int kb = ks * 32, nsh = (N == 256) ? 8 : 7;
        for (int t = tid; t < 32 * N; t += 256) {
            int r = t >> nsh, col = t & (N - 1);
            tile[r * N + col] = f2b(src[(kb + r) * N + col]);   // coalesced in col
        }
        __syncthreads();
        const int nout = (N >> 4) * 64;
        for (int o = tid; o < nout; o += 256) {
            int nt = o >> 6, lane = o & 63;
            int n = nt * 16 + (lane & 15), k0 = (lane >> 4) << 3;
            unsigned e[8];
            #pragma unroll
            for (int j = 0; j < 8; j++) e[j] = tile[(k0 + j) * N + n];
            uint4 pk;
            pk.x = e[0] | (e[1] << 16); pk.y = e[2] | (e[3] << 16);
            pk.z = e[4] | (e[5] << 16); pk.w = e[6] | (e[7] << 16);
            *(uint4*)(dst + ((nt * KS + ks) * 64 + lane) * 8) = pk;   // coalesced
        }
    } else if (c == 520) {
        for (int t = tid; t < 1024; t += 256) {
            int v = t >> 5, ci = t & 31;
            float x = edge[t];
            float m = (v == ci) ? 0.0f : x;   // diag logit masked -> adj diag = 0.5
            adjT[ci * 32 + v] = __builtin_amdgcn_rcpf(1.0f + __expf(-2.0f * m));
        }
    } else {
        int sb = c - 521;                     // 2048 sub-blocks: 32 vars x 64 groups
        int i = sb >> 6, g = sb & 63, d = tid;
        float w[64];
        #pragma unroll
        for (int k = 0; k < 64; k++) w[k] = neW[(i * 64 + k) * 256 + d];
        float bias = neb[i * 256 + d];
        for (int bb = 0; bb < 8; bb++) {
            int b = g * 8 + bb;
            const float* nr = noise + (b * 32 + i) * 64;
            float a0 = bias, a1 = 0.f, a2 = 0.f, a3 = 0.f;
            #pragma unroll
            for (int k = 0; k < 16; k++) {      // 4 independent fma chains
                a0 += nr[4 * k + 0] * w[4 * k + 0];
                a1 += nr[4 * k + 1] * w[4 * k + 1];
                a2 += nr[4 * k + 2] * w[4 * k + 2];
                a3 += nr[4 * k + 3] * w[4 * k + 3];
            }
            outp[(b * 32 + i) * 256 + d] = gelu_e((a0 + a1) + (a2 + a3));
        }
    }
}

#define MFMA16(a, b, c) __builtin_amdgcn_mfma_f32_16x16x32_bf16(a, b, c, 0, 0, 0)

// ---------------------------------------------------------------------------
// Main: 256 blocks x 1024 threads (16 waves), 1 block/CU, 2 batch rows/block.
// Stage map: A: pa (16 waves, 1 N-tile each)
//            B: W1 (waves 0-7) || delta-pc full sum (waves 8-11)
//            C: W2 (waves 0-7) || emb(ni) load (waves 8-11)
//            D: W3 (16 waves, 1 N-tile each) -> vals rows 0,1
//            E: pc fixup -> Xs(ni) (waves 8-11).  lgkm-only barriers.
// ---------------------------------------------------------------------------
__global__ __launch_bounds__(1024) void
scm_main(const float* __restrict__ emb, const float* __restrict__ pab,
         const float* __restrict__ mb1, const float* __restrict__ mb2,
         const float* __restrict__ mb3, const float* __restrict__ adjT,
         const __bf16* __restrict__ wsbf, float* __restrict__ outp) {
    __shared__ unsigned short valsS[2 * 32 * 256];   // [row][var][256 d]  32 KB
    __shared__ unsigned short Xs[2 * 264];
    __shared__ unsigned short X2[2 * 264];
    __shared__ unsigned short Hs1[2 * 136];
    __shared__ unsigned short Hs2[2 * 136];

    const int tid = threadIdx.x, blk = blockIdx.x;

    {   // zero vals (32 KB)
        uint4 z; z.x = z.y = z.z = z.w = 0;
        for (int k = tid; k < 2048; k += 1024) ((uint4*)valsS)[k] = z;
    }

    const int wid = tid >> 6, lane = tid & 63, l15 = lane & 15, q = lane >> 4;
    const int arow = l15 & 1;               // A-frag row (rows 2..15 alias, discarded)
    const int n = wid * 16 + l15;           // 0..255 (pa / W3 column)
    const int n7 = (wid & 7) * 16 + l15;    // 0..127 (W1 / W2 column)
    const int pcg = tid - 512;
    const int pcrow = (pcg >> 7) & 1, pcc = pcg & 127;
    const bool pcact = (tid >= 512) && (tid < 768);   // waves 8-11

    const float pb = pab[n];

    // seed Xs for step 0: vals = 0 -> pc = 0 -> X = emb_0 (both rows)
    if (tid < 512) {
        int r = tid >> 8, cc = tid & 255;
        Xs[r * 264 + cc] = f2b(emb[cc]);
    }
    bar_lds();

    for (int s = 0; s < 3 * N_VARS; s++) {
        const int i = s & 31, ni = (s + 1) & 31;
        const bool last = s >= 64;
        const float* __restrict__ an = adjT + ni * 32;     // wave-uniform s_load

        // ---- step-top prefetch: all step-i streamed globals ----
        float b3 = mb3[i * 256 + n];
        float bi1 = 0.f, bi2 = 0.f;
        bf16x8 w1f[8], w2f[4];
        if (wid < 8) {
            bi1 = mb1[i * 128 + n7];
            bi2 = mb2[i * 128 + n7];
            #pragma unroll
            for (int ks = 0; ks < 8; ks++)
                w1f[ks] = *(const bf16x8*)(wsbf + ELOFF_W1 + (size_t)i * 32768 +
                                           ((wid * 8 + ks) * 64 + lane) * 8);
            #pragma unroll
            for (int ks = 0; ks < 4; ks++)
                w2f[ks] = *(const bf16x8*)(wsbf + ELOFF_W2 + (size_t)i * 16384 +
                                           ((wid * 4 + ks) * 64 + lane) * 8);
        }
        bf16x8 paf[8];
        #pragma unroll
        for (int ks = 0; ks < 8; ks++)
            paf[ks] = *(const bf16x8*)(wsbf + ELOFF_PA + ((wid * 8 + ks) * 64 + lane) * 8);
        bf16x8 w3f[4];
        #pragma unroll
        for (int ks = 0; ks < 4; ks++)
            w3f[ks] = *(const bf16x8*)(wsbf + ELOFF_W3 + (size_t)i * 32768 +
                                       ((wid * 4 + ks) * 64 + lane) * 8);
        float ne0 = 0.f, ne1 = 0.f;
        size_t ob = 0;
        if (q == 0) {
            ob = ((size_t)(blk * 2) * 32 + i) * 256 + n;
            ne0 = outp[ob];
            ne1 = outp[ob + 8192];          // row 1 = +32*256
        }

        // ==== A: pa = gelu(X @ pa_W + pa_b)  (16 waves, nt = wid) ====
        {
            f32x4 acc = {0, 0, 0, 0};
            #pragma unroll
            for (int ks = 0; ks < 8; ks++) {
                bf16x8 af = *(const bf16x8*)(Xs + arow * 264 + ks * 32 + q * 8);
                acc = MFMA16(af, paf[ks], acc);
            }
            if (q == 0) {
                X2[n]       = f2b(gelu_e(acc[0] + pb));
                X2[264 + n] = f2b(gelu_e(acc[1] + pb));
            }
        }
        bar_lds();

        // ==== B: W1 (waves 0-7) || delta-pc full sum + old_i (waves 8-11) ====
        float p0 = 0.f, p1 = 0.f, of0 = 0.f, of1 = 0.f;
        if (wid < 8) {
            f32x4 aa = {0, 0, 0, 0}, ab = {0, 0, 0, 0};
            #pragma unroll
            for (int ks = 0; ks < 8; ks += 2) {
                bf16x8 af0 = *(const bf16x8*)(X2 + arow * 264 + ks * 32 + q * 8);
                bf16x8 af1 = *(const bf16x8*)(X2 + arow * 264 + (ks + 1) * 32 + q * 8);
                aa = MFMA16(af0, w1f[ks], aa);
                ab = MFMA16(af1, w1f[ks + 1], ab);
            }
            if (q == 0) {
                Hs1[n7]       = f2b(gelu_e(aa[0] + ab[0] + bi1));
                Hs1[136 + n7] = f2b(gelu_e(aa[1] + ab[1] + bi1));
            }
        } else if (pcact) {
            const unsigned short* vp = valsS + pcrow * 8192 + pcc * 2;
            #pragma unroll
            for (int v = 0; v < 32; v++) {
                unsigned u = *(const unsigned*)(vp + v * 256);
                float sc = an[v];
                p0 += sc * __uint_as_float(u << 16);
                p1 += sc * __uint_as_float(u & 0xFFFF0000u);
            }
            unsigned uo = *(const unsigned*)(valsS + pcrow * 8192 + i * 256 + pcc * 2);
            of0 = __uint_as_float(uo << 16);
            of1 = __uint_as_float(uo & 0xFFFF0000u);
        }
        bar_lds();

        // ==== C: W2 (waves 0-7) || emb(ni) load (waves 8-11) ====
        float2 e2n = {0.f, 0.f};
        if (pcact) e2n = *(const float2*)(emb + ni * 256 + pcc * 2);
        if (wid < 8) {
            f32x4 acc = {0, 0, 0, 0};
            #pragma unroll
            for (int ks = 0; ks < 4; ks++) {
                bf16x8 af = *(const bf16x8*)(Hs1 + arow * 136 + ks * 32 + q * 8);
                acc = MFMA16(af, w2f[ks], acc);
            }
            if (q == 0) {
                Hs2[n7]       = f2b(gelu_e(acc[0] + bi2));
                Hs2[136 + n7] = f2b(gelu_e(acc[1] + bi2));
            }
        }
        bar_lds();

        // ==== D: W3 (16 waves, nt = wid) + b3 + NE -> vals rows 0,1 ====
        {
            f32x4 acc = {0, 0, 0, 0};
            #pragma unroll
            for (int ks = 0; ks < 4; ks++) {
                bf16x8 af = *(const bf16x8*)(Hs2 + arow * 136 + ks * 32 + q * 8);
                acc = MFMA16(af, w3f[ks], acc);
            }
            if (q == 0) {
                float v0 = acc[0] + b3 + ne0;
                float v1 = acc[1] + b3 + ne1;
                valsS[i * 256 + n]        = f2b(v0);
                valsS[8192 + i * 256 + n] = f2b(v1);
                if (last) {
                    outp[ob]        = v0;
                    outp[ob + 8192] = v1;
                }
            }
        }
        bar_lds();

        // ==== E: pc delta fixup -> Xs for step ni (waves 8-11) ====
        if (pcact) {
            unsigned un = *(const unsigned*)(valsS + pcrow * 8192 + i * 256 + pcc * 2);
            float av = an[i];                        // a[i, ni]
            float x0 = p0 + av * (__uint_as_float(un << 16)          - of0) + e2n.x;
            float x1 = p1 + av * (__uint_as_float(un & 0xFFFF0000u)  - of1) + e2n.y;
            *(unsigned*)(Xs + pcrow * 264 + pcc * 2) =
                (unsigned)f2b(x0) | ((unsigned)f2b(x1) << 16);
        }
        bar_lds();
    }
}

extern "C" void kernel_launch(void* const* d_in, const int* in_sizes, int n_in,
                              void* d_out, int out_size, void* d_ws, size_t ws_size,
                              hipStream_t stream) {
    (void)in_sizes; (void)n_in; (void)out_size; (void)ws_size;
    const float* noise = (const float*)d_in[0];
    const float* edge  = (const float*)d_in[1];
    const float* emb   = (const float*)d_in[2];
    const float* paW   = (const float*)d_in[3];
    const float* pab   = (const float*)d_in[4];
    const float* mW1   = (const float*)d_in[5];
    const float* mb1   = (const float*)d_in[6];
    const float* mW2   = (const float*)d_in[7];
    const float* mb2   = (const float*)d_in[8];
    const float* mW3   = (const float*)d_in[9];
    const float* mb3   = (const float*)d_in[10];
    const float* neW   = (const float*)d_in[11];
    const float* neb   = (const float*)d_in[12];
    float* outp = (float*)d_out;

    float* adjT = (float*)d_ws;
    unsigned short* wsb = (unsigned short*)((char*)d_ws + 4096);

    prep_all<<<2569, 256, 0, stream>>>(paW, mW1, mW2, mW3, edge, wsb, adjT,
                                       noise, neW, neb, outp);
    scm_main<<<NBLK, 1024, 0, stream>>>(emb, pab, mb1, mb2, mb3, adjT,
                                        (const __bf16*)wsb, outp);
}